// Round 1
// baseline (195.635 us; speedup 1.0000x reference)
//
#include <hip/hip_runtime.h>
#include <hip/hip_bf16.h>

#define E_EDGES 300000
#define N_NODES 50000
#define BE 256          // edges per block
#define KC 512          // K-chunk of the 4096-deep GEMM
#define NCHUNK 8
#define HID 128

typedef short short8 __attribute__((ext_vector_type(8)));
typedef float f32x16 __attribute__((ext_vector_type(16)));

__device__ __forceinline__ unsigned short bfs(float f) {
  __hip_bfloat16 h = __float2bfloat16(f);
  return *reinterpret_cast<unsigned short*>(&h);
}
__device__ __forceinline__ float bf2f(unsigned short b) {
  return __uint_as_float(((unsigned)b) << 16);
}

// Build an A-fragment for mfma_f32_32x32x16_bf16: 8 bf16 = h * x[w0..w0+8)
__device__ __forceinline__ short8 mk_frag(float h, const float4 lo, const float4 hi4) {
  short8 s;
  s[0] = (short)bfs(h * lo.x);
  s[1] = (short)bfs(h * lo.y);
  s[2] = (short)bfs(h * lo.z);
  s[3] = (short)bfs(h * lo.w);
  s[4] = (short)bfs(h * hi4.x);
  s[5] = (short)bfs(h * hi4.y);
  s[6] = (short)bfs(h * hi4.z);
  s[7] = (short)bfs(h * hi4.w);
  return s;
}

// ---------------------------------------------------------------------------
// Prep: W2 (128x1024 f32, == W2f (4096x32) row-major) -> bf16, transposed to
// [v][klocal] per 512-deep chunk, XOR-swizzled, as a linear LDS image in ws.
// Also b2 -> B2T[v][w] bf16 image (no swizzle) at ws+262144.
// ---------------------------------------------------------------------------
__global__ void prep_w2t(const float* __restrict__ W2, const float* __restrict__ b2,
                         char* __restrict__ ws) {
  int tid = blockIdx.x * 256 + threadIdx.x;
  if (tid < 65536) {                 // 8 chunks * 32 v * 256 pairs
    int c = tid >> 13;
    int r = tid & 8191;
    int kp = r >> 5;                 // pair index within chunk: 0..255
    int v  = r & 31;
    int klocal = kp * 2;
    int kg = c * KC + klocal;        // global K index 0..4095
    float a = W2[(size_t)kg * 32 + v];
    float b = W2[(size_t)(kg + 1) * 32 + v];
    unsigned u = ((unsigned)bfs(a)) | (((unsigned)bfs(b)) << 16);
    int byteoff = c * 32768 + v * 1024 + ((klocal * 2) ^ ((v & 7) << 4));
    *(unsigned*)(ws + byteoff) = u;
  } else if (tid < 65536 + 512) {    // bias: 32 v * 16 pairs
    int i = tid - 65536;
    int wp = i >> 5;
    int v  = i & 31;
    int w  = wp * 2;
    unsigned u = ((unsigned)bfs(b2[w * 32 + v])) | (((unsigned)bfs(b2[(w + 1) * 32 + v])) << 16);
    *(unsigned*)(ws + 262144 + v * 64 + w * 2) = u;
  }
}

// ---------------------------------------------------------------------------
// Main fused kernel: h-MLP -> implicit G = h (x) xj -> GEMM vs W2 -> bias ->
// atomic scatter into receivers.
// ---------------------------------------------------------------------------
__launch_bounds__(256, 1)
__global__ void nnconv_main(const float* __restrict__ x,
                            const int* __restrict__ senders,
                            const int* __restrict__ receivers,
                            const float* __restrict__ edge_attr,
                            const float* __restrict__ W1,
                            const float* __restrict__ b1,
                            const char* __restrict__ ws,
                            float* __restrict__ out) {
  __shared__ unsigned short h_lds[HID][BE];          // 64 KB, [k][e] bf16
  __shared__ char w2t[2][32768];                     // 64 KB double-buffered B chunk
  __shared__ char biasT[2048];                       // B2T image
  __shared__ __align__(16) float w1b1[6 * HID + HID];// W1 then b1
  __shared__ int rcv_lds[BE];

  const int t    = threadIdx.x;
  const int wid  = t >> 6;
  const int lane = t & 63;
  const int col  = lane & 31;
  const int hi   = lane >> 5;
  const int E0   = blockIdx.x * BE;

  // ---- stage W1 / b1 into LDS
  if (t < 192) {
    float4 v4 = ((const float4*)W1)[t];
    *(float4*)&w1b1[t * 4] = v4;
  } else if (t < 224) {
    float4 v4 = ((const float4*)b1)[t - 192];
    *(float4*)&w1b1[768 + (t - 192) * 4] = v4;
  }
  // ---- bias image -> LDS (linear copy)
  if (t < 128) {
    *(float4*)(biasT + t * 16) = *(const float4*)(ws + 262144 + t * 16);
  }
  // ---- receivers -> LDS (tail marked -1)
  {
    int ge = E0 + t;
    rcv_lds[t] = (ge < E_EDGES) ? receivers[ge] : -1;
  }
  // ---- issue async stage of chunk 0
  {
    const char* gsrc = ws + wid * 8192;
    char* lbase = ((char*)&w2t[0][0]) + wid * 8192;
#pragma unroll
    for (int it = 0; it < 8; ++it)
      __builtin_amdgcn_global_load_lds(
          (const __attribute__((address_space(1))) void*)(gsrc + it * 1024 + lane * 16),
          (__attribute__((address_space(3))) void*)(lbase + it * 1024), 16, 0, 0);
  }

  // ---- gather x_j rows for this lane's two edge tiles (only the hi-half slices needed)
  const int el0 = wid * 64 + col;
  const int el1 = el0 + 32;
  const int ge0 = min(E0 + el0, E_EDGES - 1);
  const int ge1 = min(E0 + el1, E_EDGES - 1);
  const float* row0 = x + (size_t)senders[ge0] * 32;
  const float* row1 = x + (size_t)senders[ge1] * 32;
  const float4 xA0lo = *(const float4*)(row0 + hi * 8);
  const float4 xA0hi = *(const float4*)(row0 + hi * 8 + 4);
  const float4 xB0lo = *(const float4*)(row0 + 16 + hi * 8);
  const float4 xB0hi = *(const float4*)(row0 + 16 + hi * 8 + 4);
  const float4 xA1lo = *(const float4*)(row1 + hi * 8);
  const float4 xA1hi = *(const float4*)(row1 + hi * 8 + 4);
  const float4 xB1lo = *(const float4*)(row1 + 16 + hi * 8);
  const float4 xB1hi = *(const float4*)(row1 + 16 + hi * 8 + 4);

  __syncthreads();   // w1b1 ready

  // ---- edge MLP: thread t owns edge E0+t, computes h[0..127], stores bf16 [k][e]
  {
    int ge = min(E0 + t, E_EDGES - 1);
    const float* ea = edge_attr + (size_t)ge * 6;
    float ev[6];
#pragma unroll
    for (int d = 0; d < 6; ++d) ev[d] = ea[d];
#pragma unroll 2
    for (int j = 0; j < HID; j += 4) {
      float4 acc4 = *(const float4*)&w1b1[768 + j];
#pragma unroll
      for (int d = 0; d < 6; ++d) {
        float4 w4 = *(const float4*)&w1b1[d * HID + j];
        acc4.x += ev[d] * w4.x;
        acc4.y += ev[d] * w4.y;
        acc4.z += ev[d] * w4.z;
        acc4.w += ev[d] * w4.w;
      }
      h_lds[j + 0][t] = bfs(fmaxf(acc4.x, 0.f));
      h_lds[j + 1][t] = bfs(fmaxf(acc4.y, 0.f));
      h_lds[j + 2][t] = bfs(fmaxf(acc4.z, 0.f));
      h_lds[j + 3][t] = bfs(fmaxf(acc4.w, 0.f));
    }
  }

  __syncthreads();   // h_lds + chunk0 (vmcnt drained by barrier) ready

  f32x16 acc0 = {};
  f32x16 acc1 = {};
  const int sw = (col & 7) << 4;
  int buf = 0;

#pragma unroll 1
  for (int c = 0; c < NCHUNK; ++c) {
    if (c + 1 < NCHUNK) {  // prefetch next chunk into other buffer (overlaps compute)
      const char* gsrc = ws + (c + 1) * 32768 + wid * 8192;
      char* lbase = ((char*)&w2t[buf ^ 1][0]) + wid * 8192;
#pragma unroll
      for (int it = 0; it < 8; ++it)
        __builtin_amdgcn_global_load_lds(
            (const __attribute__((address_space(1))) void*)(gsrc + it * 1024 + lane * 16),
            (__attribute__((address_space(3))) void*)(lbase + it * 1024), 16, 0, 0);
    }
    const char* Bb = &w2t[buf][0];
#pragma unroll
    for (int k16 = 0; k16 < 16; ++k16) {
      const int kg = c * 16 + k16;                       // h index 0..127
      const float h0 = bf2f(h_lds[kg][el0]);
      const float h1 = bf2f(h_lds[kg][el1]);
      const int kb0 = (k16 * 32 + hi * 8) * 2;           // byte offset pre-XOR
      const int kb1 = kb0 + 32;
      const short8 B0 = *(const short8*)(Bb + col * 1024 + (kb0 ^ sw));
      const short8 B1 = *(const short8*)(Bb + col * 1024 + (kb1 ^ sw));
      const short8 A00 = mk_frag(h0, xA0lo, xA0hi);
      const short8 A10 = mk_frag(h1, xA1lo, xA1hi);
      const short8 A01 = mk_frag(h0, xB0lo, xB0hi);
      const short8 A11 = mk_frag(h1, xB1lo, xB1hi);
      acc0 = __builtin_amdgcn_mfma_f32_32x32x16_bf16(A00, B0, acc0, 0, 0, 0);
      acc1 = __builtin_amdgcn_mfma_f32_32x32x16_bf16(A10, B0, acc1, 0, 0, 0);
      acc0 = __builtin_amdgcn_mfma_f32_32x32x16_bf16(A01, B1, acc0, 0, 0, 0);
      acc1 = __builtin_amdgcn_mfma_f32_32x32x16_bf16(A11, B1, acc1, 0, 0, 0);
    }
    __syncthreads();   // drains prefetch vmcnt + protects buffer reuse
    buf ^= 1;
  }

  // ---- bias: two extra MFMA steps with h == 1 (B2T staged linear, unswizzled)
  {
    const short8 Bb0 = *(const short8*)(biasT + col * 64 + hi * 16);
    const short8 Bb1 = *(const short8*)(biasT + col * 64 + 32 + hi * 16);
    const short8 A00 = mk_frag(1.f, xA0lo, xA0hi);
    const short8 A10 = mk_frag(1.f, xA1lo, xA1hi);
    const short8 A01 = mk_frag(1.f, xB0lo, xB0hi);
    const short8 A11 = mk_frag(1.f, xB1lo, xB1hi);
    acc0 = __builtin_amdgcn_mfma_f32_32x32x16_bf16(A00, Bb0, acc0, 0, 0, 0);
    acc1 = __builtin_amdgcn_mfma_f32_32x32x16_bf16(A10, Bb0, acc1, 0, 0, 0);
    acc0 = __builtin_amdgcn_mfma_f32_32x32x16_bf16(A01, Bb1, acc0, 0, 0, 0);
    acc1 = __builtin_amdgcn_mfma_f32_32x32x16_bf16(A11, Bb1, acc1, 0, 0, 0);
  }

  // ---- scatter: C/D layout col=lane&31, row=(r&3)+8*(r>>2)+4*hi (m74/m101)
#pragma unroll
  for (int r = 0; r < 16; ++r) {
    const int row = (r & 3) + 8 * (r >> 2) + 4 * hi;
    const int rcv0 = rcv_lds[wid * 64 + row];
    if (rcv0 >= 0) atomicAdd(out + (size_t)rcv0 * 32 + col, acc0[r]);
    const int rcv1 = rcv_lds[wid * 64 + 32 + row];
    if (rcv1 >= 0) atomicAdd(out + (size_t)rcv1 * 32 + col, acc1[r]);
  }
}

extern "C" void kernel_launch(void* const* d_in, const int* in_sizes, int n_in,
                              void* d_out, int out_size, void* d_ws, size_t ws_size,
                              hipStream_t stream) {
  const float* x         = (const float*)d_in[0];
  const int*   senders   = (const int*)d_in[1];
  const int*   receivers = (const int*)d_in[2];
  const float* edge_attr = (const float*)d_in[3];
  const float* W1        = (const float*)d_in[4];
  const float* b1        = (const float*)d_in[5];
  const float* W2        = (const float*)d_in[6];
  const float* b2        = (const float*)d_in[7];
  float* out = (float*)d_out;
  char*  ws  = (char*)d_ws;

  hipMemsetAsync(out, 0, (size_t)N_NODES * 32 * sizeof(float), stream);
  prep_w2t<<<258, 256, 0, stream>>>(W2, b2, ws);
  nnconv_main<<<(E_EDGES + BE - 1) / BE, 256, 0, stream>>>(
      x, senders, receivers, edge_attr, W1, b1, ws, out);
}

// Round 3
// 96.580 us; speedup vs baseline: 2.0256x; 2.0256x over previous
//
#include <hip/hip_runtime.h>
#include <hip/hip_bf16.h>

#define E_EDGES 300000
#define N_NODES 50000
#define BE 256
#define KC 256              // K-depth per chunk (of 4096)
#define NCHUNK 16
#define CHUNK_BYTES 16384   // 32 v * 256 k * 2B
#define BIAS_OFF 262144

typedef _Float16 h2 __attribute__((ext_vector_type(2)));
typedef _Float16 h8 __attribute__((ext_vector_type(8)));
typedef float f32x16 __attribute__((ext_vector_type(16)));

static __device__ __forceinline__ unsigned short f2h(float f) {
  _Float16 h = (_Float16)f;
  return __builtin_bit_cast(unsigned short, h);
}
static __device__ __forceinline__ h2 cvt2(float a, float b) {
  auto r = __builtin_amdgcn_cvt_pkrtz(a, b);   // __fp16 ext_vector(2)
  return __builtin_bit_cast(h2, r);
}
static __device__ __forceinline__ h2 dup_lo(unsigned u) {
  h2 p = __builtin_bit_cast(h2, u);
  return (h2){p[0], p[0]};
}
static __device__ __forceinline__ h2 dup_hi(unsigned u) {
  h2 p = __builtin_bit_cast(h2, u);
  return (h2){p[1], p[1]};
}
// A-fragment = hd (broadcast h pair) * 4 packed x pairs -> 4 v_pk_mul_f16
static __device__ __forceinline__ h8 mk4(h2 hd, h2 p0, h2 p1, h2 p2, h2 p3) {
  h2 m0 = hd * p0, m1 = hd * p1, m2 = hd * p2, m3 = hd * p3;
  return (h8){m0[0], m0[1], m1[0], m1[1], m2[0], m2[1], m3[0], m3[1]};
}
static __device__ __forceinline__ h8 pk4(h2 p0, h2 p1, h2 p2, h2 p3) {
  return (h8){p0[0], p0[1], p1[0], p1[1], p2[0], p2[1], p3[0], p3[1]};
}

// ---------------------------------------------------------------------------
// Prep: W2 (viewed flat as (4096,32) row-major) -> f16, transposed to
// [v][klocal] per 256-deep chunk, XOR-swizzled ((v&31)<<4 on 16B granules),
// stored as a linear image in ws. Bias b2 -> [v][w] f16 image at BIAS_OFF.
// ---------------------------------------------------------------------------
__global__ void prep_w2t(const float* __restrict__ W2, const float* __restrict__ b2,
                         char* __restrict__ ws) {
  int tid = blockIdx.x * 256 + threadIdx.x;
  if (tid < 65536) {                  // 16 chunks * 32 v * 128 k-pairs
    int c   = tid >> 12;
    int rem = tid & 4095;
    int v   = rem >> 7;               // 0..31
    int kp  = rem & 127;              // k-pair within chunk
    int kg2 = c * KC + kp * 2;        // global K index
    unsigned u = (unsigned)f2h(W2[(size_t)kg2 * 32 + v]) |
                 ((unsigned)f2h(W2[(size_t)(kg2 + 1) * 32 + v]) << 16);
    int off = c * CHUNK_BYTES + v * 512 + ((kp * 4) ^ ((v & 31) << 4));
    *(unsigned*)(ws + off) = u;
  } else if (tid < 65536 + 512) {     // bias: 32 v * 16 w-pairs
    int i  = tid - 65536;
    int v  = i & 31;
    int wp = i >> 5;
    int w  = wp * 2;
    unsigned u = (unsigned)f2h(b2[w * 32 + v]) |
                 ((unsigned)f2h(b2[(w + 1) * 32 + v]) << 16);
    *(unsigned*)(ws + BIAS_OFF + v * 64 + wp * 4) = u;
  }
}

// ---------------------------------------------------------------------------
// Fused main: per-chunk h recompute (in-thread) -> __shfl broadcast ->
// pk_mul A-frags -> f16 MFMA vs LDS-staged W2 chunk -> bias MFMA -> scatter.
// ---------------------------------------------------------------------------
__launch_bounds__(256, 4)
__global__ void nnconv_main(const float* __restrict__ x,
                            const int* __restrict__ senders,
                            const int* __restrict__ receivers,
                            const float* __restrict__ edge_attr,
                            const float* __restrict__ W1,
                            const float* __restrict__ b1,
                            const char* __restrict__ ws,
                            float* __restrict__ out) {
  __shared__ __align__(16) char w2t[2][CHUNK_BYTES];
  __shared__ int rcv_lds[BE];

  const int t    = threadIdx.x;
  const int wid  = t >> 6;
  const int lane = t & 63;
  const int col  = lane & 31;
  const int hi   = lane >> 5;
  const int E0   = blockIdx.x * BE;

  // ---- issue async stage of chunk 0 (earliest)
  {
    const char* g = ws;
    char* l = &w2t[0][0];
#pragma unroll
    for (int it = 0; it < 4; ++it)
      __builtin_amdgcn_global_load_lds(
          (const __attribute__((address_space(1))) void*)(g + it * 4096 + t * 16),
          (__attribute__((address_space(3))) void*)(l + it * 4096 + t * 16), 16, 0, 0);
  }

  rcv_lds[t] = (E0 + t < E_EDGES) ? receivers[E0 + t] : -1;

  // ---- own edge attributes (for h recompute)
  const int ge_own = min(E0 + t, E_EDGES - 1);
  const float2* eap = (const float2*)(edge_attr + (size_t)ge_own * 6);
  const float2 ea01 = eap[0], ea23 = eap[1], ea45 = eap[2];
  const float ev[6] = {ea01.x, ea01.y, ea23.x, ea23.y, ea45.x, ea45.y};

  // ---- gather x_j slices for this lane's two edge rows, convert to f16 pairs
  const int el0 = wid * 64 + col;
  const int el1 = el0 + 32;
  const int ge0 = min(E0 + el0, E_EDGES - 1);
  const int ge1 = min(E0 + el1, E_EDGES - 1);
  const float* row0 = x + (size_t)senders[ge0] * 32;
  const float* row1 = x + (size_t)senders[ge1] * 32;
  float4 fa, fb;
  fa = *(const float4*)(row0 + hi * 8);      fb = *(const float4*)(row0 + hi * 8 + 4);
  const h2 xA0[4] = {cvt2(fa.x, fa.y), cvt2(fa.z, fa.w), cvt2(fb.x, fb.y), cvt2(fb.z, fb.w)};
  fa = *(const float4*)(row0 + 16 + hi * 8); fb = *(const float4*)(row0 + 16 + hi * 8 + 4);
  const h2 xB0[4] = {cvt2(fa.x, fa.y), cvt2(fa.z, fa.w), cvt2(fb.x, fb.y), cvt2(fb.z, fb.w)};
  fa = *(const float4*)(row1 + hi * 8);      fb = *(const float4*)(row1 + hi * 8 + 4);
  const h2 xA1[4] = {cvt2(fa.x, fa.y), cvt2(fa.z, fa.w), cvt2(fb.x, fb.y), cvt2(fb.z, fb.w)};
  fa = *(const float4*)(row1 + 16 + hi * 8); fb = *(const float4*)(row1 + 16 + hi * 8 + 4);
  const h2 xB1[4] = {cvt2(fa.x, fa.y), cvt2(fa.z, fa.w), cvt2(fb.x, fb.y), cvt2(fb.z, fb.w)};

  __syncthreads();   // rcv + chunk0 (barrier drains vmcnt) ready

  f32x16 acc0 = {};
  f32x16 acc1 = {};
  const int swB = (col & 31) << 4;
  int buf = 0;

#pragma unroll 1
  for (int c = 0; c < NCHUNK; ++c) {
    if (c + 1 < NCHUNK) {   // prefetch next chunk into other buffer
      const char* g = ws + (c + 1) * CHUNK_BYTES;
      char* l = &w2t[buf ^ 1][0];
#pragma unroll
      for (int it = 0; it < 4; ++it)
        __builtin_amdgcn_global_load_lds(
            (const __attribute__((address_space(1))) void*)(g + it * 4096 + t * 16),
            (__attribute__((address_space(3))) void*)(l + it * 4096 + t * 16), 16, 0, 0);
    }

    // ---- recompute own h[c*8 .. c*8+8) (uniform W1/b1 addresses -> scalar loads)
    float hv[8];
    {
      const float* bp = b1 + c * 8;
      const float4 b0 = *(const float4*)bp, b4 = *(const float4*)(bp + 4);
      hv[0] = b0.x; hv[1] = b0.y; hv[2] = b0.z; hv[3] = b0.w;
      hv[4] = b4.x; hv[5] = b4.y; hv[6] = b4.z; hv[7] = b4.w;
#pragma unroll
      for (int d = 0; d < 6; ++d) {
        const float* wp = W1 + d * 128 + c * 8;
        const float4 w0 = *(const float4*)wp, w4 = *(const float4*)(wp + 4);
        hv[0] += ev[d] * w0.x; hv[1] += ev[d] * w0.y;
        hv[2] += ev[d] * w0.z; hv[3] += ev[d] * w0.w;
        hv[4] += ev[d] * w4.x; hv[5] += ev[d] * w4.y;
        hv[6] += ev[d] * w4.z; hv[7] += ev[d] * w4.w;
      }
    }
    unsigned hp[4];
#pragma unroll
    for (int q = 0; q < 4; ++q)
      hp[q] = __builtin_bit_cast(unsigned,
                cvt2(fmaxf(hv[q * 2], 0.f), fmaxf(hv[q * 2 + 1], 0.f)));

    // ---- broadcast h to the lanes that own edges el0/el1 (in-wave shuffles)
    h2 hdA[8], hdB[8];
#pragma unroll
    for (int q = 0; q < 4; ++q) {
      const unsigned ua = __shfl(hp[q], col);
      const unsigned ub = __shfl(hp[q], col + 32);
      hdA[q * 2] = dup_lo(ua); hdA[q * 2 + 1] = dup_hi(ua);
      hdB[q * 2] = dup_lo(ub); hdB[q * 2 + 1] = dup_hi(ub);
    }

    // ---- 16 K-steps over this chunk
    const char* Bb = &w2t[buf][0] + col * 512;
#pragma unroll
    for (int s = 0; s < 16; ++s) {
      const h8 B = *(const h8*)(Bb + ((s * 32 + hi * 16) ^ swB));
      const int kq = s >> 1;
      h8 A0, A1;
      if (s & 1) {
        A0 = mk4(hdA[kq], xB0[0], xB0[1], xB0[2], xB0[3]);
        A1 = mk4(hdB[kq], xB1[0], xB1[1], xB1[2], xB1[3]);
      } else {
        A0 = mk4(hdA[kq], xA0[0], xA0[1], xA0[2], xA0[3]);
        A1 = mk4(hdB[kq], xA1[0], xA1[1], xA1[2], xA1[3]);
      }
      acc0 = __builtin_amdgcn_mfma_f32_32x32x16_f16(A0, B, acc0, 0, 0, 0);
      acc1 = __builtin_amdgcn_mfma_f32_32x32x16_f16(A1, B, acc1, 0, 0, 0);
    }
    __syncthreads();   // drains prefetch + protects buffer reuse
    buf ^= 1;
  }

  // ---- bias: two extra MFMA K-steps (h == 1), B-frags straight from global
  {
    const char* bb = ws + BIAS_OFF + col * 64;
    const h8 B0 = *(const h8*)(bb + hi * 16);
    const h8 B1 = *(const h8*)(bb + 32 + hi * 16);
    const h8 A00 = pk4(xA0[0], xA0[1], xA0[2], xA0[3]);
    const h8 A10 = pk4(xA1[0], xA1[1], xA1[2], xA1[3]);
    const h8 A01 = pk4(xB0[0], xB0[1], xB0[2], xB0[3]);
    const h8 A11 = pk4(xB1[0], xB1[1], xB1[2], xB1[3]);
    acc0 = __builtin_amdgcn_mfma_f32_32x32x16_f16(A00, B0, acc0, 0, 0, 0);
    acc1 = __builtin_amdgcn_mfma_f32_32x32x16_f16(A10, B0, acc1, 0, 0, 0);
    acc0 = __builtin_amdgcn_mfma_f32_32x32x16_f16(A01, B1, acc0, 0, 0, 0);
    acc1 = __builtin_amdgcn_mfma_f32_32x32x16_f16(A11, B1, acc1, 0, 0, 0);
  }

  // ---- scatter: C/D layout col=lane&31, row=(r&3)+8*(r>>2)+4*hi
#pragma unroll
  for (int r = 0; r < 16; ++r) {
    const int row = (r & 3) + 8 * (r >> 2) + 4 * hi;
    const int rcv0 = rcv_lds[wid * 64 + row];
    if (rcv0 >= 0) atomicAdd(out + (size_t)rcv0 * 32 + col, acc0[r]);
    const int rcv1 = rcv_lds[wid * 64 + 32 + row];
    if (rcv1 >= 0) atomicAdd(out + (size_t)rcv1 * 32 + col, acc1[r]);
  }
}

extern "C" void kernel_launch(void* const* d_in, const int* in_sizes, int n_in,
                              void* d_out, int out_size, void* d_ws, size_t ws_size,
                              hipStream_t stream) {
  const float* x         = (const float*)d_in[0];
  const int*   senders   = (const int*)d_in[1];
  const int*   receivers = (const int*)d_in[2];
  const float* edge_attr = (const float*)d_in[3];
  const float* W1        = (const float*)d_in[4];
  const float* b1        = (const float*)d_in[5];
  const float* W2        = (const float*)d_in[6];
  const float* b2        = (const float*)d_in[7];
  float* out = (float*)d_out;
  char*  ws  = (char*)d_ws;

  (void)hipMemsetAsync(out, 0, (size_t)N_NODES * 32 * sizeof(float), stream);
  prep_w2t<<<259, 256, 0, stream>>>(W2, b2, ws);
  nnconv_main<<<(E_EDGES + BE - 1) / BE, 256, 0, stream>>>(
      x, senders, receivers, edge_attr, W1, b1, ws, out);
}